// Round 4
// baseline (296.698 us; speedup 1.0000x reference)
//
#include <hip/hip_runtime.h>
#include <hip/hip_bf16.h>
#include <hip/hip_cooperative_groups.h>

namespace cg = cooperative_groups;

#define N_ROWS 8192
#define DIM 256
#define NUM_CLASSES 64
#define NBLK 64                        // 8192/128 row/col blocks
#define NTRI (NBLK * (NBLK + 1) / 2)   // 2080 upper-triangle tiles
#define COOP_GRID 512

typedef __bf16 bf16x8 __attribute__((ext_vector_type(8)));
typedef float f32x4 __attribute__((ext_vector_type(4)));

__device__ __forceinline__ unsigned short f2bf(float f) {
  unsigned int u = __float_as_uint(f);
  u += 0x7fffu + ((u >> 16) & 1u);   // round-to-nearest-even
  return (unsigned short)(u >> 16);
}
__device__ __forceinline__ float bf2f(unsigned short h) {
  return __uint_as_float(((unsigned int)h) << 16);
}

__device__ __forceinline__ void gload_lds16(const unsigned short* g, unsigned short* l) {
  __builtin_amdgcn_global_load_lds(
      (const __attribute__((address_space(1))) unsigned int*)g,
      (__attribute__((address_space(3))) unsigned int*)l, 16, 0, 0);
}

__device__ __forceinline__ void tri_decode(int q, int& I, int& J) {
  int i = (int)((129.0f - sqrtf(16641.0f - 8.0f * (float)q)) * 0.5f);
  while (i * (129 - i) / 2 > q) --i;
  while ((i + 1) * (128 - i) / 2 <= q) ++i;
  I = i;
  J = i + (q - i * (129 - i) / 2);
}

// ============================ fused cooperative kernel ============================
// P1: bf16 quantize + per-row scale s_i = sqrt((log2e/t)/ss_i) (ss from the
//     quantized values so the diagonal stays exact) + sliced label histogram.
// P2: persistent loop over upper-triangle 128x128 Gram tiles; double-buffered
//     global_load_lds staging with cross-tile prefetch (next tile's first K-slab
//     staged during kb=7 / epilogue); fused exp2 epilogue emits row partials for
//     rowblock I and col partials for rowblock J (each tile computed once).
// P3: per-row loss terms; P4: final scalar.
__global__ void __launch_bounds__(256, 3) fused_kernel(
    const float* __restrict__ x, const int* __restrict__ lab,
    const float* __restrict__ tptr, unsigned short* __restrict__ xb,
    float* __restrict__ sv, int* __restrict__ hpart, float* __restrict__ part,
    float* __restrict__ bsum, float* __restrict__ out) {
  __shared__ alignas(16) unsigned short Alds[2][4096];  // 16 KiB
  __shared__ alignas(16) unsigned short Blds[2][4096];  // 16 KiB

  const int tid = threadIdx.x;
  const int wave = tid >> 6;
  const int lane = tid & 63;
  const int quad = lane >> 4;
  const int lc = lane & 15;
  cg::grid_group grid = cg::this_grid();

  // ---------------- P1: prep ----------------
  {
    const float C = 1.4426950408889634f / tptr[0];  // log2(e)/t
    for (int rq = blockIdx.x; rq < N_ROWS / 4; rq += gridDim.x) {
      const int row = rq * 4 + wave;
      const float4 v =
          *reinterpret_cast<const float4*>(x + (size_t)row * DIM + lane * 4);
      const unsigned short q0 = f2bf(v.x), q1 = f2bf(v.y), q2 = f2bf(v.z),
                           q3 = f2bf(v.w);
      const float f0 = bf2f(q0), f1 = bf2f(q1), f2 = bf2f(q2), f3 = bf2f(q3);
      float ss = f0 * f0 + f1 * f1 + f2 * f2 + f3 * f3;
      ushort4 u4; u4.x = q0; u4.y = q1; u4.z = q2; u4.w = q3;
      *reinterpret_cast<ushort4*>(xb + (size_t)row * DIM + lane * 4) = u4;
      for (int m = 32; m; m >>= 1) ss += __shfl_xor(ss, m, 64);
      if (lane == 0) sv[row] = sqrtf(C / ss);
    }
    if (blockIdx.x < 32) {  // sliced histogram: 256 labels per block, no contention
      int* h = reinterpret_cast<int*>(&Blds[0][0]);
      if (tid < NUM_CLASSES) h[tid] = 0;
      __syncthreads();
      atomicAdd(&h[lab[blockIdx.x * 256 + tid]], 1);
      __syncthreads();
      if (tid < NUM_CLASSES) hpart[blockIdx.x * NUM_CLASSES + tid] = h[tid];
    }
  }
  grid.sync();

  // ---------------- P2: Gram tiles ----------------
  {
    const int wrow = (wave >> 1) * 64;
    const int wcol = (wave & 1) * 64;
    const int srow = lane >> 2;       // 16 rows per staging instruction
    const int sseg = (lane & 3) * 8;  // 4 x 16B segments per 32-elem row
    // epilogue scratch aliases BUFFER 1 only (buf0 holds the next tile's prefetch)
    float* red = reinterpret_cast<float*>(&Alds[1][0]);            // 256 floats
    float (*colred)[128][2] = reinterpret_cast<float (*)[128][2]>(&Blds[1][0]);

#define STAGE(rb, cb, kb, b)                                                  \
  {                                                                           \
    const int k0 = (kb) * 32;                                                 \
    const unsigned short* gA =                                                \
        xb + (size_t)((rb) + wave * 32 + srow) * DIM + k0 + sseg;             \
    gload_lds16(gA, &Alds[b][(wave * 32) * 32]);                              \
    gload_lds16(gA + 16 * DIM, &Alds[b][(wave * 32 + 16) * 32]);              \
    const unsigned short* gB =                                                \
        xb + (size_t)((cb) + wave * 32 + srow) * DIM + k0 + sseg;             \
    gload_lds16(gB, &Blds[b][(wave * 32) * 32]);                              \
    gload_lds16(gB + 16 * DIM, &Blds[b][(wave * 32 + 16) * 32]);              \
  }

    int q = blockIdx.x;
    int I, J;
    tri_decode(q, I, J);
    int rowBase = I * 128, colBase = J * 128;
    STAGE(rowBase, colBase, 0, 0)

    while (q < NTRI) {
      const int qn = q + gridDim.x;
      const bool hasNext = qn < NTRI;
      int In = 0, Jn = 0, rowN = 0, colN = 0;
      if (hasNext) { tri_decode(qn, In, Jn); rowN = In * 128; colN = Jn * 128; }

      f32x4 acc[4][4];
      const f32x4 zero4 = {0.f, 0.f, 0.f, 0.f};
      for (int mi = 0; mi < 4; ++mi)
        for (int ni = 0; ni < 4; ++ni) acc[mi][ni] = zero4;

      for (int kb = 0; kb < 8; ++kb) {
        __syncthreads();  // staging(kb) visible; prior readers of this buf done
        if (kb < 7) STAGE(rowBase, colBase, kb + 1, (kb + 1) & 1)
        else if (hasNext) STAGE(rowN, colN, 0, 0)  // prefetch next tile into buf0
        const unsigned short* Ab = &Alds[kb & 1][0];
        const unsigned short* Bb = &Blds[kb & 1][0];
        bf16x8 afr[4], bfr[4];
        for (int mi = 0; mi < 4; ++mi)
          afr[mi] = *reinterpret_cast<const bf16x8*>(
              &Ab[(wrow + mi * 16 + lc) * 32 + quad * 8]);
        for (int ni = 0; ni < 4; ++ni)
          bfr[ni] = *reinterpret_cast<const bf16x8*>(
              &Bb[(wcol + ni * 16 + lc) * 32 + quad * 8]);
        for (int mi = 0; mi < 4; ++mi)
          for (int ni = 0; ni < 4; ++ni)
            acc[mi][ni] = __builtin_amdgcn_mfma_f32_16x16x32_bf16(
                afr[mi], bfr[ni], acc[mi][ni], 0, 0, 0);
      }
      __syncthreads();  // all compute done; buf1 becomes epilogue scratch

      red[tid] = 0.f;
      __syncthreads();

      float scol[4];
      int labc[4];
      for (int ni = 0; ni < 4; ++ni) {
        const int c = colBase + wcol + ni * 16 + lc;
        scol[ni] = sv[c];
        labc[ni] = lab[c];
      }
      float ctot[4] = {0.f, 0.f, 0.f, 0.f};
      float csame[4] = {0.f, 0.f, 0.f, 0.f};

      for (int mi = 0; mi < 4; ++mi) {
        for (int r = 0; r < 4; ++r) {
          const int lr = wrow + mi * 16 + quad * 4 + r;  // C/D row mapping
          const int grow = rowBase + lr;
          const float si = sv[grow];
          const int li = lab[grow];
          float st = 0.f, sm = 0.f;
          for (int ni = 0; ni < 4; ++ni) {
            const float e = exp2f(acc[mi][ni][r] * si * scol[ni]);
            const float em = (li == labc[ni]) ? e : 0.f;
            st += e;
            sm += em;
            ctot[ni] += e;
            csame[ni] += em;
          }
          for (int m = 8; m; m >>= 1) {
            st += __shfl_xor(st, m, 64);
            sm += __shfl_xor(sm, m, 64);
          }
          if (lc == 0) {
            atomicAdd(&red[lr], st);
            atomicAdd(&red[128 + lr], sm);
          }
        }
      }

      if (J > I) {
        for (int ni = 0; ni < 4; ++ni) {
          float t2 = ctot[ni] + __shfl_xor(ctot[ni], 16, 64);
          t2 += __shfl_xor(t2, 32, 64);
          float s2 = csame[ni] + __shfl_xor(csame[ni], 16, 64);
          s2 += __shfl_xor(s2, 32, 64);
          if (quad == 0) {
            colred[0][wcol + ni * 16 + lc][wave >> 1] = t2;
            colred[1][wcol + ni * 16 + lc][wave >> 1] = s2;
          }
        }
      }
      __syncthreads();
      if (tid < 128) {
        part[(size_t)J * N_ROWS + rowBase + tid] = red[tid];
        part[(size_t)(64 + J) * N_ROWS + rowBase + tid] = red[128 + tid];
        if (J > I) {
          part[(size_t)I * N_ROWS + colBase + tid] =
              colred[0][tid][0] + colred[0][tid][1];
          part[(size_t)(64 + I) * N_ROWS + colBase + tid] =
              colred[1][tid][0] + colred[1][tid][1];
        }
      }
      // next iteration's first __syncthreads() protects buf1 reuse
      q = qn; I = In; J = Jn; rowBase = rowN; colBase = colN;
    }
#undef STAGE
  }
  grid.sync();

  // ---------------- P3: row loss ----------------
  if (blockIdx.x < 32) {
    int* h = reinterpret_cast<int*>(&Alds[0][0]);
    float* wsum = reinterpret_cast<float*>(&Blds[0][0]);
    if (tid < NUM_CLASSES) {
      int s = 0;
      for (int k = 0; k < 32; ++k) s += hpart[k * NUM_CLASSES + tid];
      h[tid] = s;
    }
    __syncthreads();
    const int row = blockIdx.x * 256 + tid;
    float st = 0.f, sm = 0.f;
#pragma unroll 8
    for (int b = 0; b < 64; ++b) {
      st += part[(size_t)b * N_ROWS + row];
      sm += part[(size_t)(64 + b) * N_ROWS + row];
    }
    const int c = h[lab[row]];
    const float pos = sm + (float)(N_ROWS - c);
    const float neg = (st - sm) + (float)c;
    float term = logf(neg) - logf(pos);
    for (int m = 32; m; m >>= 1) term += __shfl_xor(term, m, 64);
    if (lane == 0) wsum[wave] = term;
    __syncthreads();
    if (tid == 0) {
      bsum[blockIdx.x] = wsum[0] + wsum[1] + wsum[2] + wsum[3];
      __threadfence();
    }
  }
  grid.sync();

  // ---------------- P4: final scalar ----------------
  if (blockIdx.x == 0 && tid < 64) {
    float v = (tid < 32) ? bsum[tid] : 0.f;
    for (int m = 32; m; m >>= 1) v += __shfl_xor(v, m, 64);
    if (tid == 0) out[0] = v * (1.0f / (float)N_ROWS);
  }
}

// ============================ fallback path (R3, known-good) ============================
__global__ void __launch_bounds__(256) prep_kernel(
    const float* __restrict__ x, const float* __restrict__ tptr,
    unsigned short* __restrict__ xb, float* __restrict__ sv,
    float* __restrict__ gsum, unsigned int* __restrict__ gcnt) {
  if (blockIdx.x == 0 && threadIdx.x == 0) { *gsum = 0.f; *gcnt = 0u; }
  const int row = blockIdx.x * 4 + (threadIdx.x >> 6);
  const int lane = threadIdx.x & 63;
  const float4 v = *reinterpret_cast<const float4*>(x + (size_t)row * DIM + lane * 4);
  const unsigned short q0 = f2bf(v.x), q1 = f2bf(v.y), q2 = f2bf(v.z), q3 = f2bf(v.w);
  const float f0 = bf2f(q0), f1 = bf2f(q1), f2 = bf2f(q2), f3 = bf2f(q3);
  float ss = f0 * f0 + f1 * f1 + f2 * f2 + f3 * f3;
  ushort4 u4; u4.x = q0; u4.y = q1; u4.z = q2; u4.w = q3;
  *reinterpret_cast<ushort4*>(xb + (size_t)row * DIM + lane * 4) = u4;
  for (int m = 32; m; m >>= 1) ss += __shfl_xor(ss, m, 64);
  if (lane == 0) sv[row] = sqrtf(1.4426950408889634f / tptr[0] / ss);
}

__global__ void __launch_bounds__(256, 3) main_kernel(
    const unsigned short* __restrict__ xb, const float* __restrict__ sv,
    const int* __restrict__ lab, float* __restrict__ part) {
  const int q = blockIdx.x;
  int I, J;
  tri_decode(q, I, J);

  __shared__ alignas(16) unsigned short Alds[128 * 32];
  __shared__ alignas(16) unsigned short Blds[128 * 32];
  float* red = reinterpret_cast<float*>(Alds);
  float (*colred)[128][2] = reinterpret_cast<float (*)[128][2]>(Blds);

  const int tid = threadIdx.x;
  const int wave = tid >> 6;
  const int lane = tid & 63;
  const int quad = lane >> 4;
  const int lc = lane & 15;
  const int wrow = (wave >> 1) * 64;
  const int wcol = (wave & 1) * 64;
  const int rowBase = I * 128;
  const int colBase = J * 128;

  f32x4 acc[4][4];
  const f32x4 zero4 = {0.f, 0.f, 0.f, 0.f};
  for (int mi = 0; mi < 4; ++mi)
    for (int ni = 0; ni < 4; ++ni) acc[mi][ni] = zero4;

  const int srow = lane >> 2;
  const int sseg = (lane & 3) * 8;

  for (int kb = 0; kb < 8; ++kb) {
    const int k0 = kb * 32;
    const unsigned short* gA =
        xb + (size_t)(rowBase + wave * 32 + srow) * DIM + k0 + sseg;
    gload_lds16(gA, &Alds[(wave * 32) * 32]);
    gload_lds16(gA + 16 * DIM, &Alds[(wave * 32 + 16) * 32]);
    const unsigned short* gB =
        xb + (size_t)(colBase + wave * 32 + srow) * DIM + k0 + sseg;
    gload_lds16(gB, &Blds[(wave * 32) * 32]);
    gload_lds16(gB + 16 * DIM, &Blds[(wave * 32 + 16) * 32]);
    __syncthreads();
    bf16x8 afr[4], bfr[4];
    for (int mi = 0; mi < 4; ++mi)
      afr[mi] = *reinterpret_cast<const bf16x8*>(
          &Alds[(wrow + mi * 16 + lc) * 32 + quad * 8]);
    for (int ni = 0; ni < 4; ++ni)
      bfr[ni] = *reinterpret_cast<const bf16x8*>(
          &Blds[(wcol + ni * 16 + lc) * 32 + quad * 8]);
    for (int mi = 0; mi < 4; ++mi)
      for (int ni = 0; ni < 4; ++ni)
        acc[mi][ni] = __builtin_amdgcn_mfma_f32_16x16x32_bf16(
            afr[mi], bfr[ni], acc[mi][ni], 0, 0, 0);
    __syncthreads();
  }

  red[tid] = 0.f;
  __syncthreads();

  float scol[4];
  int labc[4];
  for (int ni = 0; ni < 4; ++ni) {
    const int c = colBase + wcol + ni * 16 + lc;
    scol[ni] = sv[c];
    labc[ni] = lab[c];
  }
  float ctot[4] = {0.f, 0.f, 0.f, 0.f};
  float csame[4] = {0.f, 0.f, 0.f, 0.f};

  for (int mi = 0; mi < 4; ++mi) {
    for (int r = 0; r < 4; ++r) {
      const int lr = wrow + mi * 16 + quad * 4 + r;
      const int grow = rowBase + lr;
      const float si = sv[grow];
      const int li = lab[grow];
      float st = 0.f, sm = 0.f;
      for (int ni = 0; ni < 4; ++ni) {
        const float e = exp2f(acc[mi][ni][r] * si * scol[ni]);
        const float em = (li == labc[ni]) ? e : 0.f;
        st += e; sm += em; ctot[ni] += e; csame[ni] += em;
      }
      for (int m = 8; m; m >>= 1) {
        st += __shfl_xor(st, m, 64);
        sm += __shfl_xor(sm, m, 64);
      }
      if (lc == 0) {
        atomicAdd(&red[lr], st);
        atomicAdd(&red[128 + lr], sm);
      }
    }
  }

  if (J > I) {
    for (int ni = 0; ni < 4; ++ni) {
      float t2 = ctot[ni] + __shfl_xor(ctot[ni], 16, 64);
      t2 += __shfl_xor(t2, 32, 64);
      float s2 = csame[ni] + __shfl_xor(csame[ni], 16, 64);
      s2 += __shfl_xor(s2, 32, 64);
      if (quad == 0) {
        colred[0][wcol + ni * 16 + lc][wave >> 1] = t2;
        colred[1][wcol + ni * 16 + lc][wave >> 1] = s2;
      }
    }
  }
  __syncthreads();
  if (tid < 128) {
    part[(size_t)J * N_ROWS + rowBase + tid] = red[tid];
    part[(size_t)(64 + J) * N_ROWS + rowBase + tid] = red[128 + tid];
    if (J > I) {
      part[(size_t)I * N_ROWS + colBase + tid] =
          colred[0][tid][0] + colred[0][tid][1];
      part[(size_t)(64 + I) * N_ROWS + colBase + tid] =
          colred[1][tid][0] + colred[1][tid][1];
    }
  }
}

__global__ void __launch_bounds__(256) row_loss_kernel(
    const float* __restrict__ part, const int* __restrict__ lab,
    float* __restrict__ gsum, unsigned int* __restrict__ gcnt,
    float* __restrict__ out) {
  __shared__ int h[NUM_CLASSES];
  if (threadIdx.x < NUM_CLASSES) h[threadIdx.x] = 0;
  __syncthreads();
  for (int i = threadIdx.x; i < N_ROWS; i += 256) atomicAdd(&h[lab[i]], 1);
  __syncthreads();

  const int row = blockIdx.x * 256 + threadIdx.x;
  float st = 0.f, sm = 0.f;
  for (int b = 0; b < 64; ++b) {
    st += part[(size_t)b * N_ROWS + row];
    sm += part[(size_t)(64 + b) * N_ROWS + row];
  }
  const int c = h[lab[row]];
  const float pos = sm + (float)(N_ROWS - c);
  const float neg = (st - sm) + (float)c;
  float term = logf(neg) - logf(pos);
  for (int m = 32; m; m >>= 1) term += __shfl_xor(term, m, 64);
  __shared__ float wsum[4];
  const int lane = threadIdx.x & 63;
  const int wave = threadIdx.x >> 6;
  if (lane == 0) wsum[wave] = term;
  __syncthreads();
  if (threadIdx.x == 0) {
    const float bs = wsum[0] + wsum[1] + wsum[2] + wsum[3];
    atomicAdd(gsum, bs);
    __threadfence();
    const unsigned int t = atomicAdd(gcnt, 1u);
    if (t == (unsigned int)(N_ROWS / 256 - 1)) {
      const float total = atomicAdd(gsum, 0.0f);
      out[0] = total * (1.0f / (float)N_ROWS);
    }
  }
}

extern "C" void kernel_launch(void* const* d_in, const int* in_sizes, int n_in,
                              void* d_out, int out_size, void* d_ws, size_t ws_size,
                              hipStream_t stream) {
  const float* x = (const float*)d_in[0];
  const int* lab = (const int*)d_in[1];
  const float* t = (const float*)d_in[2];
  float* out = (float*)d_out;

  char* ws = (char*)d_ws;
  unsigned short* xb = (unsigned short*)ws;                          // 4 MiB
  float* sv = (float*)(ws + (4u << 20));                             // 32 KiB
  float* part = (float*)(ws + (4u << 20) + (32u << 10));             // 4 MiB
  int* hpart = (int*)(ws + (8u << 20) + (32u << 10));                // 8 KiB
  float* bsum = (float*)(ws + (8u << 20) + (40u << 10));             // 128 B
  float* gsum = (float*)(ws + (8u << 20) + (41u << 10));
  unsigned int* gcnt = (unsigned int*)(ws + (8u << 20) + (41u << 10) + 8);

  void* args[] = {(void*)&x,  (void*)&lab,   (void*)&t,    (void*)&xb,
                  (void*)&sv, (void*)&hpart, (void*)&part, (void*)&bsum,
                  (void*)&out};
  hipError_t err = hipLaunchCooperativeKernel(
      (const void*)fused_kernel, dim3(COOP_GRID), dim3(256), args, 0, stream);
  if (err != hipSuccess) {
    // fallback: known-good 3-kernel path
    prep_kernel<<<N_ROWS / 4, 256, 0, stream>>>(x, t, xb, sv, gsum, gcnt);
    main_kernel<<<NTRI, 256, 0, stream>>>(xb, sv, lab, part);
    row_loss_kernel<<<N_ROWS / 256, 256, 0, stream>>>(part, lab, gsum, gcnt, out);
  }
}

// Round 5
// 107.534 us; speedup vs baseline: 2.7591x; 2.7591x over previous
//
#include <hip/hip_runtime.h>
#include <hip/hip_bf16.h>

#define N_ROWS 8192
#define DIM 256
#define NUM_CLASSES 64
#define NBLK 64                        // 8192/128 row/col blocks
#define NTRI (NBLK * (NBLK + 1) / 2)   // 2080 upper-triangle tiles
#define SCR_PITCH 36                   // 32 data + pad; 144B row stride (16B aligned)

typedef __bf16 bf16x8 __attribute__((ext_vector_type(8)));
typedef float f32x4 __attribute__((ext_vector_type(4)));

__device__ __forceinline__ unsigned short f2bf(float f) {
  unsigned int u = __float_as_uint(f);
  u += 0x7fffu + ((u >> 16) & 1u);   // round-to-nearest-even
  return (unsigned short)(u >> 16);
}
__device__ __forceinline__ float bf2f(unsigned short h) {
  return __uint_as_float(((unsigned int)h) << 16);
}

__device__ __forceinline__ void gload_lds16(const unsigned short* g, unsigned short* l) {
  __builtin_amdgcn_global_load_lds(
      (const __attribute__((address_space(1))) unsigned int*)g,
      (__attribute__((address_space(3))) unsigned int*)l, 16, 0, 0);
}

__device__ __forceinline__ void tri_decode(int q, int& I, int& J) {
  int i = (int)((129.0f - sqrtf(16641.0f - 8.0f * (float)q)) * 0.5f);
  while (i * (129 - i) / 2 > q) --i;
  while ((i + 1) * (128 - i) / 2 <= q) ++i;
  I = i;
  J = i + (q - i * (129 - i) / 2);
}

// Kernel 1: quantize to bf16, per-row sum-of-squares of the *quantized* values
// (keeps diagonal cos exact), scale s_i = sqrt((log2e/t)/ss_i). Block 0 zeroes
// the cross-kernel accumulator used by row_loss.
__global__ void __launch_bounds__(256) prep_kernel(
    const float* __restrict__ x, const float* __restrict__ tptr,
    unsigned short* __restrict__ xb, float* __restrict__ sv,
    float* __restrict__ gsum, unsigned int* __restrict__ gcnt) {
  if (blockIdx.x == 0 && threadIdx.x == 0) { *gsum = 0.f; *gcnt = 0u; }
  const int row = blockIdx.x * 4 + (threadIdx.x >> 6);
  const int lane = threadIdx.x & 63;
  const float4 v = *reinterpret_cast<const float4*>(x + (size_t)row * DIM + lane * 4);
  const unsigned short q0 = f2bf(v.x), q1 = f2bf(v.y), q2 = f2bf(v.z), q3 = f2bf(v.w);
  const float f0 = bf2f(q0), f1 = bf2f(q1), f2 = bf2f(q2), f3 = bf2f(q3);
  float ss = f0 * f0 + f1 * f1 + f2 * f2 + f3 * f3;
  ushort4 u4; u4.x = q0; u4.y = q1; u4.z = q2; u4.w = q3;
  *reinterpret_cast<ushort4*>(xb + (size_t)row * DIM + lane * 4) = u4;
  for (int m = 32; m; m >>= 1) ss += __shfl_xor(ss, m, 64);
  if (lane == 0) sv[row] = sqrtf(1.4426950408889634f / tptr[0] / ss);
}

// Kernel 2: upper-triangle 128x128 Gram tiles (bf16 MFMA 16x16x32), 1D
// triangular grid, single-buffered staging (R3 K-loop, proven). Epilogue v2:
// no shuffle-butterflies — lanes write 4-col partials to padded LDS scratch,
// one barrier, 128 owner threads sum 32 floats via ds_read_b128 and store
// finished row partials. Col partials (J>I) via 2-step shuffle (cheap).
__global__ void __launch_bounds__(256, 3) main_kernel(
    const unsigned short* __restrict__ xb, const float* __restrict__ sv,
    const int* __restrict__ lab, float* __restrict__ part) {
  const int q = blockIdx.x;
  int I, J;
  tri_decode(q, I, J);

  // scr[0] = S_tot scratch, scr[1] = S_same scratch; staging buffers alias scr[0..]
  __shared__ alignas(16) float scr[2][128 * SCR_PITCH];  // 36,864 B
  __shared__ float colred[2][128][2];                    // 2 KiB
  __shared__ float rsv[128]; __shared__ int rlab[128];   // tile-row scales/labels
  __shared__ float csv[128]; __shared__ int clab[128];   // tile-col scales/labels
  unsigned short* Alds = reinterpret_cast<unsigned short*>(&scr[0][0]);        // 8 KiB
  unsigned short* Blds = reinterpret_cast<unsigned short*>(
      reinterpret_cast<char*>(&scr[0][0]) + 8192);                             // 8 KiB

  const int tid = threadIdx.x;
  const int wave = tid >> 6;
  const int lane = tid & 63;
  const int quad = lane >> 4;
  const int lc = lane & 15;
  const int wrow = (wave >> 1) * 64;
  const int wcol = (wave & 1) * 64;
  const int ch = wave & 1;  // column half this wave covers
  const int rowBase = I * 128;
  const int colBase = J * 128;

  f32x4 acc[4][4];
  const f32x4 zero4 = {0.f, 0.f, 0.f, 0.f};
  for (int mi = 0; mi < 4; ++mi)
    for (int ni = 0; ni < 4; ++ni) acc[mi][ni] = zero4;

  const int srow = lane >> 2;       // 16 rows per staging instruction
  const int sseg = (lane & 3) * 8;  // 4 x 16B segments per 32-elem row

  for (int kb = 0; kb < 8; ++kb) {
    const int k0 = kb * 32;
    const unsigned short* gA =
        xb + (size_t)(rowBase + wave * 32 + srow) * DIM + k0 + sseg;
    gload_lds16(gA, &Alds[(wave * 32) * 32]);
    gload_lds16(gA + 16 * DIM, &Alds[(wave * 32 + 16) * 32]);
    const unsigned short* gB =
        xb + (size_t)(colBase + wave * 32 + srow) * DIM + k0 + sseg;
    gload_lds16(gB, &Blds[(wave * 32) * 32]);
    gload_lds16(gB + 16 * DIM, &Blds[(wave * 32 + 16) * 32]);
    __syncthreads();  // staged data visible
    bf16x8 afr[4], bfr[4];
    for (int mi = 0; mi < 4; ++mi)
      afr[mi] = *reinterpret_cast<const bf16x8*>(
          &Alds[(wrow + mi * 16 + lc) * 32 + quad * 8]);
    for (int ni = 0; ni < 4; ++ni)
      bfr[ni] = *reinterpret_cast<const bf16x8*>(
          &Blds[(wcol + ni * 16 + lc) * 32 + quad * 8]);
    for (int mi = 0; mi < 4; ++mi)
      for (int ni = 0; ni < 4; ++ni)
        acc[mi][ni] = __builtin_amdgcn_mfma_f32_16x16x32_bf16(
            afr[mi], bfr[ni], acc[mi][ni], 0, 0, 0);
    __syncthreads();  // readers done before next stage overwrites
  }

  // --- stage row/col scales+labels into LDS (staging buffers now dead) ---
  if (tid < 128) {
    rsv[tid] = sv[rowBase + tid];
    rlab[tid] = lab[rowBase + tid];
    csv[tid] = sv[colBase + tid];
    clab[tid] = lab[colBase + tid];
  }
  __syncthreads();

  float scol[4];
  int labc[4];
#pragma unroll
  for (int ni = 0; ni < 4; ++ni) {
    scol[ni] = csv[wcol + ni * 16 + lc];
    labc[ni] = clab[wcol + ni * 16 + lc];
  }
  float ctot[4] = {0.f, 0.f, 0.f, 0.f};
  float csame[4] = {0.f, 0.f, 0.f, 0.f};

#pragma unroll
  for (int mi = 0; mi < 4; ++mi) {
#pragma unroll
    for (int r = 0; r < 4; ++r) {
      const int lr = wrow + mi * 16 + quad * 4 + r;  // C/D: row=(lane>>4)*4+reg
      const float siv = rsv[lr];
      const int li = rlab[lr];
      float st = 0.f, sm = 0.f;
#pragma unroll
      for (int ni = 0; ni < 4; ++ni) {
        const float e = exp2f(acc[mi][ni][r] * (siv * scol[ni]));
        const float em = (li == labc[ni]) ? e : 0.f;
        st += e;
        sm += em;
        ctot[ni] += e;
        csame[ni] += em;
      }
      scr[0][lr * SCR_PITCH + ch * 16 + lc] = st;  // 4-col partial, unique slot
      scr[1][lr * SCR_PITCH + ch * 16 + lc] = sm;
    }
  }

  if (J > I) {  // column sums: reduce over the 16 rows this lane covered
#pragma unroll
    for (int ni = 0; ni < 4; ++ni) {
      float t2 = ctot[ni] + __shfl_xor(ctot[ni], 16, 64);
      t2 += __shfl_xor(t2, 32, 64);
      float s2 = csame[ni] + __shfl_xor(csame[ni], 16, 64);
      s2 += __shfl_xor(s2, 32, 64);
      if (quad == 0) {
        colred[0][wcol + ni * 16 + lc][wave >> 1] = t2;
        colred[1][wcol + ni * 16 + lc][wave >> 1] = s2;
      }
    }
  }
  __syncthreads();

  if (tid < 128) {  // owner thread per tile-row: finish and store
    const int base = tid * SCR_PITCH;
    f32x4 a0 = {0.f, 0.f, 0.f, 0.f}, a1 = {0.f, 0.f, 0.f, 0.f};
#pragma unroll
    for (int k = 0; k < 8; ++k)
      a0 += *reinterpret_cast<const f32x4*>(&scr[0][base + 4 * k]);
#pragma unroll
    for (int k = 0; k < 8; ++k)
      a1 += *reinterpret_cast<const f32x4*>(&scr[1][base + 4 * k]);
    const float st = a0[0] + a0[1] + a0[2] + a0[3];
    const float sm = a1[0] + a1[1] + a1[2] + a1[3];
    part[(size_t)J * N_ROWS + rowBase + tid] = st;
    part[(size_t)(64 + J) * N_ROWS + rowBase + tid] = sm;
    if (J > I) {
      part[(size_t)I * N_ROWS + colBase + tid] =
          colred[0][tid][0] + colred[0][tid][1];
      part[(size_t)(64 + I) * N_ROWS + colBase + tid] =
          colred[1][tid][0] + colred[1][tid][1];
    }
  }
}

// Kernel 3: per-row loss terms (label histogram in LDS), block sums
// accumulated device-scope; last block writes the final scalar.
__global__ void __launch_bounds__(256) row_loss_kernel(
    const float* __restrict__ part, const int* __restrict__ lab,
    float* __restrict__ gsum, unsigned int* __restrict__ gcnt,
    float* __restrict__ out) {
  __shared__ int h[NUM_CLASSES];
  if (threadIdx.x < NUM_CLASSES) h[threadIdx.x] = 0;
  __syncthreads();
  for (int i = threadIdx.x; i < N_ROWS; i += 256) atomicAdd(&h[lab[i]], 1);
  __syncthreads();

  const int row = blockIdx.x * 256 + threadIdx.x;
  float st = 0.f, sm = 0.f;
#pragma unroll 8
  for (int b = 0; b < 64; ++b) {
    st += part[(size_t)b * N_ROWS + row];
    sm += part[(size_t)(64 + b) * N_ROWS + row];
  }
  const int c = h[lab[row]];
  const float pos = sm + (float)(N_ROWS - c);
  const float neg = (st - sm) + (float)c;
  float term = logf(neg) - logf(pos);
  for (int m = 32; m; m >>= 1) term += __shfl_xor(term, m, 64);
  __shared__ float wsum[4];
  const int lane = threadIdx.x & 63;
  const int wave = threadIdx.x >> 6;
  if (lane == 0) wsum[wave] = term;
  __syncthreads();
  if (threadIdx.x == 0) {
    const float bs = wsum[0] + wsum[1] + wsum[2] + wsum[3];
    atomicAdd(gsum, bs);
    __threadfence();
    const unsigned int t = atomicAdd(gcnt, 1u);
    if (t == (unsigned int)(N_ROWS / 256 - 1)) {  // last block to arrive
      const float total = atomicAdd(gsum, 0.0f);  // coherent read
      out[0] = total * (1.0f / (float)N_ROWS);
    }
  }
}

extern "C" void kernel_launch(void* const* d_in, const int* in_sizes, int n_in,
                              void* d_out, int out_size, void* d_ws, size_t ws_size,
                              hipStream_t stream) {
  const float* x = (const float*)d_in[0];
  const int* lab = (const int*)d_in[1];
  const float* t = (const float*)d_in[2];
  float* out = (float*)d_out;

  char* ws = (char*)d_ws;
  unsigned short* xb = (unsigned short*)ws;                      // 4 MiB bf16 X
  float* sv = (float*)(ws + (4u << 20));                         // 32 KiB scales
  float* part = (float*)(ws + (4u << 20) + (32u << 10));         // 4 MiB partials
  float* gsum = (float*)(ws + (8u << 20) + (32u << 10));
  unsigned int* gcnt = (unsigned int*)(ws + (8u << 20) + (32u << 10) + 8);

  prep_kernel<<<N_ROWS / 4, 256, 0, stream>>>(x, t, xb, sv, gsum, gcnt);
  main_kernel<<<NTRI, 256, 0, stream>>>(xb, sv, lab, part);
  row_loss_kernel<<<N_ROWS / 256, 256, 0, stream>>>(part, lab, gsum, gcnt, out);
}